// Round 6
// baseline (228.823 us; speedup 1.0000x reference)
//
#include <hip/hip_runtime.h>
#include <hip/hip_fp16.h>

#define THREADS 256
#define SCAN_CHUNK 2048   // 256 threads x 8 elems
#define NBKT 8            // counter privatization buckets (~XCDs)

// ---------------- CSR build ----------------
__global__ void k_zero(int* __restrict__ hist, int total) {
    int i = blockIdx.x * blockDim.x + threadIdx.x;
    if (i < total) hist[i] = 0;
}

// bucket-privatized count: bucket = blockIdx&7 (consistent with k_fill)
__global__ void k_count(const int* __restrict__ dst, int* __restrict__ hist,
                        int e, int n_pad) {
    int i = blockIdx.x * blockDim.x + threadIdx.x;
    if (i < e) atomicAdd(&hist[(blockIdx.x & (NBKT - 1)) * n_pad + dst[i]], 1);
}

// inclusive scan of per-node totals within 2048-chunks -> rowptr[i+1]; chunk totals -> bsum
// also emits dinv[i] = rsqrt(deg+1)  (self-loop)
__global__ __launch_bounds__(256) void k_scan1(const int* __restrict__ hist,
                                               int* __restrict__ rowptr,
                                               int* __restrict__ bsum,
                                               float* __restrict__ dinv,
                                               int n, int n_pad) {
    __shared__ int s[256];
    const int t = threadIdx.x;
    const int base = blockIdx.x * SCAN_CHUNK + t * 8;
    int c[8];
    int run = 0;
#pragma unroll
    for (int k = 0; k < 8; ++k) {
        int i = base + k;
        int cv = 0;
        if (i < n) {
#pragma unroll
            for (int x = 0; x < NBKT; ++x) cv += hist[x * n_pad + i];
            dinv[i] = rsqrtf((float)(cv + 1));
        }
        run += cv;
        c[k] = run;  // running inclusive within thread
    }
    s[t] = run;
    __syncthreads();
    for (int off = 1; off < 256; off <<= 1) {
        int v = (t >= off) ? s[t - off] : 0;
        __syncthreads();
        s[t] += v;
        __syncthreads();
    }
    const int excl = s[t] - run;
#pragma unroll
    for (int k = 0; k < 8; ++k) {
        int i = base + k;
        if (i < n) rowptr[i + 1] = c[k] + excl;
    }
    if (t == 255) bsum[blockIdx.x] = s[255];
}

// exclusive scan of block sums (nb <= 256)
__global__ __launch_bounds__(256) void k_scan2(int* __restrict__ bsum, int nb) {
    __shared__ int s[256];
    const int t = threadIdx.x;
    int v0 = (t < nb) ? bsum[t] : 0;
    s[t] = v0;
    __syncthreads();
    for (int off = 1; off < 256; off <<= 1) {
        int v = (t >= off) ? s[t - off] : 0;
        __syncthreads();
        s[t] += v;
        __syncthreads();
    }
    if (t < nb) bsum[t] = s[t] - v0;  // exclusive
}

// finalize rowptr; rewrite hist[x][i] = bucket-x base (fill allocator)
__global__ __launch_bounds__(256) void k_scan3(int* __restrict__ hist,
                                               int* __restrict__ rowptr,
                                               const int* __restrict__ bsum,
                                               int n, int n_pad) {
    const int off = bsum[blockIdx.x];
    const int t = threadIdx.x;
#pragma unroll
    for (int k = 0; k < 8; ++k) {
        int i = blockIdx.x * SCAN_CHUNK + t + k * 256;
        if (i < n) {
            int h[NBKT];
            int tot = 0;
#pragma unroll
            for (int x = 0; x < NBKT; ++x) { h[x] = hist[x * n_pad + i]; tot += h[x]; }
            int incl = rowptr[i + 1] + off;
            rowptr[i + 1] = incl;
            int b = incl - tot;  // == rowptr[i]
#pragma unroll
            for (int x = 0; x < NBKT; ++x) { hist[x * n_pad + i] = b; b += h[x]; }
        }
    }
    if (blockIdx.x == 0 && t == 0) rowptr[0] = 0;
}

// bucket-privatized fill: same edge->block->bucket mapping as k_count
__global__ void k_fill(const int* __restrict__ src, const int* __restrict__ dst,
                       int* __restrict__ hist, int* __restrict__ csr_src,
                       int e, int n_pad) {
    int i = blockIdx.x * blockDim.x + threadIdx.x;
    if (i < e) {
        int pos = atomicAdd(&hist[(blockIdx.x & (NBKT - 1)) * n_pad + dst[i]], 1);
        csr_src[pos] = src[i];
    }
}

// ---------------- GEMM1: g1[n,128](fp16) = dinv[row] * (x[n,128] @ W1[128,128]) ----------------
__global__ __launch_bounds__(256) void k_gemm1(const float* __restrict__ x,
                                               const float* __restrict__ W,
                                               const float* __restrict__ dinv,
                                               __half2* __restrict__ g, int n) {
    __shared__ float Wl[64 * 128];  // 32 KB, [kk][j]
    __shared__ float xl[64 * 64];   // 16 KB, [r][kk]
    const int t  = threadIdx.x;
    const int cg = t & 31;
    const int rg = t >> 5;
    const int base = blockIdx.x * 64;

    float acc[8][4];
#pragma unroll
    for (int i = 0; i < 8; ++i)
#pragma unroll
        for (int j = 0; j < 4; ++j) acc[i][j] = 0.0f;

    for (int ph = 0; ph < 2; ++ph) {
        __syncthreads();
        {
            const float4* Wg = (const float4*)(W + ph * 64 * 128);
            float4* Ws = (float4*)Wl;
#pragma unroll
            for (int i = 0; i < 8; ++i) Ws[t + 256 * i] = Wg[t + 256 * i];
        }
#pragma unroll
        for (int i = 0; i < 4; ++i) {
            const int idx = t + 256 * i;
            const int r = idx >> 4, c4 = idx & 15;
            const int row = base + r;
            float4 v = make_float4(0.f, 0.f, 0.f, 0.f);
            if (row < n) v = *(const float4*)(x + (size_t)row * 128 + ph * 64 + c4 * 4);
            *(float4*)(xl + r * 64 + c4 * 4) = v;
        }
        __syncthreads();

        for (int k4 = 0; k4 < 16; ++k4) {
            float wv[4][4];
#pragma unroll
            for (int kk = 0; kk < 4; ++kk) {
                const float4 w4 = *(const float4*)(Wl + (k4 * 4 + kk) * 128 + cg * 4);
                wv[kk][0] = w4.x; wv[kk][1] = w4.y; wv[kk][2] = w4.z; wv[kk][3] = w4.w;
            }
#pragma unroll
            for (int i = 0; i < 8; ++i) {
                const float4 x4 = *(const float4*)(xl + (rg * 8 + i) * 64 + k4 * 4);
                const float xs[4] = {x4.x, x4.y, x4.z, x4.w};
#pragma unroll
                for (int kk = 0; kk < 4; ++kk)
#pragma unroll
                    for (int j = 0; j < 4; ++j)
                        acc[i][j] = fmaf(xs[kk], wv[kk][j], acc[i][j]);
            }
        }
    }

#pragma unroll
    for (int i = 0; i < 8; ++i) {
        const int row = base + rg * 8 + i;
        if (row < n) {
            const float dv = dinv[row];
            union { __half2 h[2]; uint2 u; } pk;
            pk.h[0] = __floats2half2_rn(acc[i][0] * dv, acc[i][1] * dv);
            pk.h[1] = __floats2half2_rn(acc[i][2] * dv, acc[i][3] * dv);
            *(uint2*)(g + (size_t)row * 64 + cg * 2) = pk.u;
        }
    }
}

// ---------------- gather1: out1[d] = b1 + dinv[d]*(g1[d] + sum_{s in N(d)} g1[s]) ----------------
__global__ __launch_bounds__(256) void k_gather1(const __half2* __restrict__ g,
                                                 const int* __restrict__ rowptr,
                                                 const int* __restrict__ csr_src,
                                                 const float* __restrict__ dinv,
                                                 const float* __restrict__ b1,
                                                 float* __restrict__ out1, int n) {
    const int wave = threadIdx.x >> 6;
    const int lane = threadIdx.x & 63;
    const int d = blockIdx.x * 4 + wave;
    if (d >= n) return;
    const int beg = rowptr[d], end = rowptr[d + 1];
    float ax = 0.f, ay = 0.f, bx = 0.f, by = 0.f;
    int p = beg;
    for (; p + 4 <= end; p += 4) {
        const int s0 = csr_src[p],     s1 = csr_src[p + 1];
        const int s2 = csr_src[p + 2], s3 = csr_src[p + 3];
        const __half2 v0 = g[(size_t)s0 * 64 + lane];
        const __half2 v1 = g[(size_t)s1 * 64 + lane];
        const __half2 v2 = g[(size_t)s2 * 64 + lane];
        const __half2 v3 = g[(size_t)s3 * 64 + lane];
        const float2 f0 = __half22float2(v0), f1 = __half22float2(v1);
        const float2 f2 = __half22float2(v2), f3 = __half22float2(v3);
        ax += f0.x + f2.x; ay += f0.y + f2.y;
        bx += f1.x + f3.x; by += f1.y + f3.y;
    }
    for (; p < end; ++p) {
        const int s0 = csr_src[p];
        const float2 f0 = __half22float2(g[(size_t)s0 * 64 + lane]);
        ax += f0.x; ay += f0.y;
    }
    const float2 fs = __half22float2(g[(size_t)d * 64 + lane]);
    ax += bx + fs.x;
    ay += by + fs.y;
    const float dd = dinv[d];
    const float2 bb = *(const float2*)(b1 + lane * 2);
    float2 r;
    r.x = fmaf(dd, ax, bb.x);
    r.y = fmaf(dd, ay, bb.y);
    *(float2*)(out1 + (size_t)d * 128 + lane * 2) = r;
}

// ---------------- GEMM2: g2[n,40](fp16) = dinv[row] * (relu(out1)[n,128] @ W2[128,40]) ----------------
__global__ __launch_bounds__(256) void k_gemm2(const float* __restrict__ h1,
                                               const float* __restrict__ W,
                                               const float* __restrict__ dinv,
                                               __half2* __restrict__ g, int n) {
    __shared__ float Wl[64 * 64];   // 16 KB, [kk][j] zero-padded j>=40
    __shared__ float xl[64 * 64];   // 16 KB, [r][kk]
    const int t  = threadIdx.x;
    const int cg = t & 15;
    const int rg = t >> 4;
    const int base = blockIdx.x * 64;

    float acc[4][4];
#pragma unroll
    for (int i = 0; i < 4; ++i)
#pragma unroll
        for (int j = 0; j < 4; ++j) acc[i][j] = 0.0f;

    for (int ph = 0; ph < 2; ++ph) {
        __syncthreads();
#pragma unroll
        for (int i = 0; i < 16; ++i) {
            const int idx = t + 256 * i;
            const int r = idx >> 6, c = idx & 63;
            Wl[idx] = (c < 40) ? W[(ph * 64 + r) * 40 + c] : 0.0f;
        }
#pragma unroll
        for (int i = 0; i < 4; ++i) {
            const int idx = t + 256 * i;
            const int r = idx >> 4, c4 = idx & 15;
            const int row = base + r;
            float4 v = make_float4(0.f, 0.f, 0.f, 0.f);
            if (row < n) {
                v = *(const float4*)(h1 + (size_t)row * 128 + ph * 64 + c4 * 4);
                v.x = fmaxf(v.x, 0.f); v.y = fmaxf(v.y, 0.f);
                v.z = fmaxf(v.z, 0.f); v.w = fmaxf(v.w, 0.f);
            }
            *(float4*)(xl + r * 64 + c4 * 4) = v;
        }
        __syncthreads();

        for (int k4 = 0; k4 < 16; ++k4) {
            float wv[4][4];
#pragma unroll
            for (int kk = 0; kk < 4; ++kk) {
                const float4 w4 = *(const float4*)(Wl + (k4 * 4 + kk) * 64 + cg * 4);
                wv[kk][0] = w4.x; wv[kk][1] = w4.y; wv[kk][2] = w4.z; wv[kk][3] = w4.w;
            }
#pragma unroll
            for (int i = 0; i < 4; ++i) {
                const float4 x4 = *(const float4*)(xl + (rg * 4 + i) * 64 + k4 * 4);
                const float xs[4] = {x4.x, x4.y, x4.z, x4.w};
#pragma unroll
                for (int kk = 0; kk < 4; ++kk)
#pragma unroll
                    for (int j = 0; j < 4; ++j)
                        acc[i][j] = fmaf(xs[kk], wv[kk][j], acc[i][j]);
            }
        }
    }

    if (cg < 10) {  // cols 4cg..4cg+3 < 40
#pragma unroll
        for (int i = 0; i < 4; ++i) {
            const int row = base + rg * 4 + i;
            if (row < n) {
                const float dv = dinv[row];
                union { __half2 h[2]; uint2 u; } pk;
                pk.h[0] = __floats2half2_rn(acc[i][0] * dv, acc[i][1] * dv);
                pk.h[1] = __floats2half2_rn(acc[i][2] * dv, acc[i][3] * dv);
                *(uint2*)(g + (size_t)row * 20 + cg * 2) = pk.u;
            }
        }
    }
}

// ---------------- gather2: out[d] = b2 + dinv[d]*(g2[d] + sum g2[s]) ----------------
__global__ __launch_bounds__(256) void k_gather2(const __half2* __restrict__ g,
                                                 const int* __restrict__ rowptr,
                                                 const int* __restrict__ csr_src,
                                                 const float* __restrict__ dinv,
                                                 const float* __restrict__ b2,
                                                 float* __restrict__ out, int n) {
    const int wave = threadIdx.x >> 6;
    const int lane = threadIdx.x & 63;
    const int d = blockIdx.x * 4 + wave;
    if (d >= n) return;
    const int f  = lane & 31;
    const int eg = lane >> 5;          // 0..1
    const int fc = (f < 20) ? f : 19;  // clamp so inactive lanes load safely
    const int beg = rowptr[d], end = rowptr[d + 1];
    float ax = 0.f, ay = 0.f;
    int p = beg + eg;
    for (; p + 2 < end; p += 4) {      // this eg handles p and p+2
        const int s0 = csr_src[p], s1 = csr_src[p + 2];
        const __half2 v0 = g[(size_t)s0 * 20 + fc];
        const __half2 v1 = g[(size_t)s1 * 20 + fc];
        const float2 f0 = __half22float2(v0), f1 = __half22float2(v1);
        ax += f0.x + f1.x;
        ay += f0.y + f1.y;
    }
    for (; p < end; p += 2) {
        const int s0 = csr_src[p];
        const float2 f0 = __half22float2(g[(size_t)s0 * 20 + fc]);
        ax += f0.x; ay += f0.y;
    }
    ax += __shfl_xor(ax, 32);
    ay += __shfl_xor(ay, 32);
    if (eg == 0 && f < 20) {
        const float2 fs = __half22float2(g[(size_t)d * 20 + f]);
        ax += fs.x; ay += fs.y;
        const float dd = dinv[d];
        const float2 bb = *(const float2*)(b2 + f * 2);
        float2 r;
        r.x = fmaf(dd, ax, bb.x);
        r.y = fmaf(dd, ay, bb.y);
        *(float2*)(out + (size_t)d * 40 + f * 2) = r;
    }
}

extern "C" void kernel_launch(void* const* d_in, const int* in_sizes, int n_in,
                              void* d_out, int out_size, void* d_ws, size_t ws_size,
                              hipStream_t stream) {
    const float* x  = (const float*)d_in[0];
    const int*   ei = (const int*)d_in[1];
    const float* W1 = (const float*)d_in[2];
    const float* b1 = (const float*)d_in[3];
    const float* W2 = (const float*)d_in[4];
    const float* b2 = (const float*)d_in[5];
    float* out = (float*)d_out;

    const int n = in_sizes[0] / 128;   // 50000
    const int e = in_sizes[1] / 2;     // 800000
    const int* src = ei;
    const int* dst = ei + e;

    const int n_pad = ((n + 63) / 64) * 64;
    const int e_pad = ((e + 63) / 64) * 64;

    // ws layout (4B units):
    //   dinv[n_pad] | rowptr[n_pad+64] | csr_src[e_pad] | g1[n_pad*64 half2] | out1[n*128]
    // hist[8*n_pad]/bsum overlay the g1 region (dead before k_gemm1 writes);
    // g2 (n*20 half2) overlays g1 (dead after k_gather1).
    float*   ws      = (float*)d_ws;
    float*   dinv    = ws;
    int*     rowptr  = (int*)(ws + n_pad);
    int*     csr_src = rowptr + n_pad + 64;
    __half2* g1      = (__half2*)(csr_src + e_pad);
    float*   out1    = (float*)(g1 + (size_t)n_pad * 64);
    int*     hist    = (int*)g1;              // overlay: 8*n_pad ints
    int*     bsum    = hist + NBKT * n_pad;   // overlay
    __half2* g2      = g1;                    // overlay

    const int nb_e    = (e + THREADS - 1) / THREADS;
    const int nb_scan = (n + SCAN_CHUNK - 1) / SCAN_CHUNK;
    const int nb_rows = (n + 63) / 64;
    const int nb_g    = (n + 3) / 4;
    const int nb_z    = (NBKT * n_pad + THREADS - 1) / THREADS;

    // CSR build (bucket-privatized counters)
    k_zero <<<nb_z, THREADS, 0, stream>>>(hist, NBKT * n_pad);
    k_count<<<nb_e, THREADS, 0, stream>>>(dst, hist, e, n_pad);
    k_scan1<<<nb_scan, 256, 0, stream>>>(hist, rowptr, bsum, dinv, n, n_pad);
    k_scan2<<<1, 256, 0, stream>>>(bsum, nb_scan);
    k_scan3<<<nb_scan, 256, 0, stream>>>(hist, rowptr, bsum, n, n_pad);
    k_fill <<<nb_e, THREADS, 0, stream>>>(src, dst, hist, csr_src, e, n_pad);

    // layer 1
    k_gemm1  <<<nb_rows, 256, 0, stream>>>(x, W1, dinv, g1, n);
    k_gather1<<<nb_g, 256, 0, stream>>>(g1, rowptr, csr_src, dinv, b1, out1, n);

    // layer 2
    k_gemm2  <<<nb_rows, 256, 0, stream>>>(out1, W2, dinv, g2, n);
    k_gather2<<<nb_g, 256, 0, stream>>>(g2, rowptr, csr_src, dinv, b2, out, n);
}

// Round 7
// 158.108 us; speedup vs baseline: 1.4473x; 1.4473x over previous
//
#include <hip/hip_runtime.h>
#include <hip/hip_fp16.h>

#define THREADS 256
#define EPB 2048   // edges per block in hist/scat (256 thr x 8)

// ================= sort-based CSR build (no global atomics) =================

// per-block LDS histogram of coarse bucket (dst>>8) -> Hmat[bucket][block]
__global__ __launch_bounds__(256) void k_hist(const int* __restrict__ dst,
                                              int* __restrict__ Hmat,
                                              int e, int nbuck, int nbpad) {
    __shared__ int h[256];
    const int t = threadIdx.x;
    h[t] = 0;
    __syncthreads();
    const int base = blockIdx.x * EPB;
#pragma unroll
    for (int k = 0; k < 8; ++k) {
        int i = base + k * 256 + t;
        if (i < e) atomicAdd(&h[dst[i] >> 8], 1);
    }
    __syncthreads();
    if (t < nbuck) Hmat[t * nbpad + blockIdx.x] = h[t];
}

// per-bucket exclusive scan over blocks: Off[b][j], total -> btot[b]  (nb <= 512)
__global__ __launch_bounds__(256) void k_bscan(const int* __restrict__ Hmat,
                                               int* __restrict__ Off,
                                               int* __restrict__ btot,
                                               int nb, int nbpad) {
    __shared__ int s[256];
    const int b = blockIdx.x, t = threadIdx.x;
    const int* H = Hmat + b * nbpad;
    const int v0 = (2 * t     < nb) ? H[2 * t]     : 0;
    const int v1 = (2 * t + 1 < nb) ? H[2 * t + 1] : 0;
    const int p = v0 + v1;
    s[t] = p;
    __syncthreads();
    for (int off = 1; off < 256; off <<= 1) {
        int w = (t >= off) ? s[t - off] : 0;
        __syncthreads();
        s[t] += w;
        __syncthreads();
    }
    const int excl = s[t] - p;
    int* O = Off + b * nbpad;
    if (2 * t     < nb) O[2 * t]     = excl;
    if (2 * t + 1 < nb) O[2 * t + 1] = excl + v0;
    if (t == 255) btot[b] = s[255];
}

// exclusive scan of bucket totals -> bbase; sentinel + rowptr[n]
__global__ __launch_bounds__(256) void k_base(const int* __restrict__ btot,
                                              int* __restrict__ bbase,
                                              int* __restrict__ rowptr,
                                              int nbuck, int n, int e) {
    __shared__ int s[256];
    const int t = threadIdx.x;
    const int v = (t < nbuck) ? btot[t] : 0;
    s[t] = v;
    __syncthreads();
    for (int off = 1; off < 256; off <<= 1) {
        int w = (t >= off) ? s[t - off] : 0;
        __syncthreads();
        s[t] += w;
        __syncthreads();
    }
    if (t < nbuck) bbase[t] = s[t] - v;
    if (t == 0) { bbase[nbuck] = e; rowptr[n] = e; }
}

// scatter (src,dst) pairs into coarse buckets; rank via LDS atomic within block
__global__ __launch_bounds__(256) void k_scat(const int* __restrict__ src,
                                              const int* __restrict__ dst,
                                              const int* __restrict__ Off,
                                              const int* __restrict__ bbase,
                                              int2* __restrict__ sorted,
                                              int e, int nbpad) {
    __shared__ int h[256];
    const int t = threadIdx.x;
    h[t] = 0;
    __syncthreads();
    const int base = blockIdx.x * EPB;
#pragma unroll
    for (int k = 0; k < 8; ++k) {
        int i = base + k * 256 + t;
        if (i < e) {
            const int d = dst[i];
            const int b = d >> 8;
            const int r = atomicAdd(&h[b], 1);
            const int pos = bbase[b] + Off[b * nbpad + blockIdx.x] + r;
            sorted[pos] = make_int2(src[i], d);
        }
    }
}

// per-bucket counting sort by dst&255 -> csr_src contiguous; emits rowptr + dinv
__global__ __launch_bounds__(256) void k_bsort(const int2* __restrict__ sorted,
                                               const int* __restrict__ bbase,
                                               int* __restrict__ csr_src,
                                               int* __restrict__ rowptr,
                                               float* __restrict__ dinv, int n) {
    __shared__ int cnt[256];
    __shared__ int s[256];
    __shared__ int fil[256];
    const int b = blockIdx.x, t = threadIdx.x;
    const int lo = bbase[b], hi = bbase[b + 1];
    cnt[t] = 0;
    __syncthreads();
    for (int p = lo + t; p < hi; p += 256) atomicAdd(&cnt[sorted[p].y & 255], 1);
    __syncthreads();
    const int c = cnt[t];
    s[t] = c;
    __syncthreads();
    for (int off = 1; off < 256; off <<= 1) {
        int w = (t >= off) ? s[t - off] : 0;
        __syncthreads();
        s[t] += w;
        __syncthreads();
    }
    const int excl = s[t] - c;
    const int node = b * 256 + t;
    if (node < n) {
        rowptr[node] = lo + excl;
        dinv[node] = rsqrtf((float)(c + 1));
    }
    fil[t] = lo + excl;
    __syncthreads();
    for (int p = lo + t; p < hi; p += 256) {
        const int2 pr = sorted[p];
        const int pos = atomicAdd(&fil[pr.y & 255], 1);
        csr_src[pos] = pr.x;
    }
}

// ---------------- GEMM1: g1[n,128](fp16) = dinv[row] * (x[n,128] @ W1[128,128]) ----------------
__global__ __launch_bounds__(256) void k_gemm1(const float* __restrict__ x,
                                               const float* __restrict__ W,
                                               const float* __restrict__ dinv,
                                               __half2* __restrict__ g, int n) {
    __shared__ float Wl[64 * 128];  // 32 KB, [kk][j]
    __shared__ float xl[64 * 64];   // 16 KB, [r][kk]
    const int t  = threadIdx.x;
    const int cg = t & 31;
    const int rg = t >> 5;
    const int base = blockIdx.x * 64;

    float acc[8][4];
#pragma unroll
    for (int i = 0; i < 8; ++i)
#pragma unroll
        for (int j = 0; j < 4; ++j) acc[i][j] = 0.0f;

    for (int ph = 0; ph < 2; ++ph) {
        __syncthreads();
        {
            const float4* Wg = (const float4*)(W + ph * 64 * 128);
            float4* Ws = (float4*)Wl;
#pragma unroll
            for (int i = 0; i < 8; ++i) Ws[t + 256 * i] = Wg[t + 256 * i];
        }
#pragma unroll
        for (int i = 0; i < 4; ++i) {
            const int idx = t + 256 * i;
            const int r = idx >> 4, c4 = idx & 15;
            const int row = base + r;
            float4 v = make_float4(0.f, 0.f, 0.f, 0.f);
            if (row < n) v = *(const float4*)(x + (size_t)row * 128 + ph * 64 + c4 * 4);
            *(float4*)(xl + r * 64 + c4 * 4) = v;
        }
        __syncthreads();

        for (int k4 = 0; k4 < 16; ++k4) {
            float wv[4][4];
#pragma unroll
            for (int kk = 0; kk < 4; ++kk) {
                const float4 w4 = *(const float4*)(Wl + (k4 * 4 + kk) * 128 + cg * 4);
                wv[kk][0] = w4.x; wv[kk][1] = w4.y; wv[kk][2] = w4.z; wv[kk][3] = w4.w;
            }
#pragma unroll
            for (int i = 0; i < 8; ++i) {
                const float4 x4 = *(const float4*)(xl + (rg * 8 + i) * 64 + k4 * 4);
                const float xs[4] = {x4.x, x4.y, x4.z, x4.w};
#pragma unroll
                for (int kk = 0; kk < 4; ++kk)
#pragma unroll
                    for (int j = 0; j < 4; ++j)
                        acc[i][j] = fmaf(xs[kk], wv[kk][j], acc[i][j]);
            }
        }
    }

#pragma unroll
    for (int i = 0; i < 8; ++i) {
        const int row = base + rg * 8 + i;
        if (row < n) {
            const float dv = dinv[row];
            union { __half2 h[2]; uint2 u; } pk;
            pk.h[0] = __floats2half2_rn(acc[i][0] * dv, acc[i][1] * dv);
            pk.h[1] = __floats2half2_rn(acc[i][2] * dv, acc[i][3] * dv);
            *(uint2*)(g + (size_t)row * 64 + cg * 2) = pk.u;
        }
    }
}

// ---------------- gather1: out1[d] = b1 + dinv[d]*(g1[d] + sum_{s in N(d)} g1[s]) ----------------
__global__ __launch_bounds__(256) void k_gather1(const __half2* __restrict__ g,
                                                 const int* __restrict__ rowptr,
                                                 const int* __restrict__ csr_src,
                                                 const float* __restrict__ dinv,
                                                 const float* __restrict__ b1,
                                                 float* __restrict__ out1, int n) {
    const int wave = threadIdx.x >> 6;
    const int lane = threadIdx.x & 63;
    const int d = blockIdx.x * 4 + wave;
    if (d >= n) return;
    const int beg = rowptr[d], end = rowptr[d + 1];
    float ax = 0.f, ay = 0.f, bx = 0.f, by = 0.f;
    int p = beg;
    for (; p + 4 <= end; p += 4) {
        const int s0 = csr_src[p],     s1 = csr_src[p + 1];
        const int s2 = csr_src[p + 2], s3 = csr_src[p + 3];
        const __half2 v0 = g[(size_t)s0 * 64 + lane];
        const __half2 v1 = g[(size_t)s1 * 64 + lane];
        const __half2 v2 = g[(size_t)s2 * 64 + lane];
        const __half2 v3 = g[(size_t)s3 * 64 + lane];
        const float2 f0 = __half22float2(v0), f1 = __half22float2(v1);
        const float2 f2 = __half22float2(v2), f3 = __half22float2(v3);
        ax += f0.x + f2.x; ay += f0.y + f2.y;
        bx += f1.x + f3.x; by += f1.y + f3.y;
    }
    for (; p < end; ++p) {
        const int s0 = csr_src[p];
        const float2 f0 = __half22float2(g[(size_t)s0 * 64 + lane]);
        ax += f0.x; ay += f0.y;
    }
    const float2 fs = __half22float2(g[(size_t)d * 64 + lane]);
    ax += bx + fs.x;
    ay += by + fs.y;
    const float dd = dinv[d];
    const float2 bb = *(const float2*)(b1 + lane * 2);
    float2 r;
    r.x = fmaf(dd, ax, bb.x);
    r.y = fmaf(dd, ay, bb.y);
    *(float2*)(out1 + (size_t)d * 128 + lane * 2) = r;
}

// ---------------- GEMM2: g2[n,40](fp16) = dinv[row] * (relu(out1)[n,128] @ W2[128,40]) ----------------
__global__ __launch_bounds__(256) void k_gemm2(const float* __restrict__ h1,
                                               const float* __restrict__ W,
                                               const float* __restrict__ dinv,
                                               __half2* __restrict__ g, int n) {
    __shared__ float Wl[64 * 64];   // 16 KB, [kk][j] zero-padded j>=40
    __shared__ float xl[64 * 64];   // 16 KB, [r][kk]
    const int t  = threadIdx.x;
    const int cg = t & 15;
    const int rg = t >> 4;
    const int base = blockIdx.x * 64;

    float acc[4][4];
#pragma unroll
    for (int i = 0; i < 4; ++i)
#pragma unroll
        for (int j = 0; j < 4; ++j) acc[i][j] = 0.0f;

    for (int ph = 0; ph < 2; ++ph) {
        __syncthreads();
#pragma unroll
        for (int i = 0; i < 16; ++i) {
            const int idx = t + 256 * i;
            const int r = idx >> 6, c = idx & 63;
            Wl[idx] = (c < 40) ? W[(ph * 64 + r) * 40 + c] : 0.0f;
        }
#pragma unroll
        for (int i = 0; i < 4; ++i) {
            const int idx = t + 256 * i;
            const int r = idx >> 4, c4 = idx & 15;
            const int row = base + r;
            float4 v = make_float4(0.f, 0.f, 0.f, 0.f);
            if (row < n) {
                v = *(const float4*)(h1 + (size_t)row * 128 + ph * 64 + c4 * 4);
                v.x = fmaxf(v.x, 0.f); v.y = fmaxf(v.y, 0.f);
                v.z = fmaxf(v.z, 0.f); v.w = fmaxf(v.w, 0.f);
            }
            *(float4*)(xl + r * 64 + c4 * 4) = v;
        }
        __syncthreads();

        for (int k4 = 0; k4 < 16; ++k4) {
            float wv[4][4];
#pragma unroll
            for (int kk = 0; kk < 4; ++kk) {
                const float4 w4 = *(const float4*)(Wl + (k4 * 4 + kk) * 64 + cg * 4);
                wv[kk][0] = w4.x; wv[kk][1] = w4.y; wv[kk][2] = w4.z; wv[kk][3] = w4.w;
            }
#pragma unroll
            for (int i = 0; i < 4; ++i) {
                const float4 x4 = *(const float4*)(xl + (rg * 4 + i) * 64 + k4 * 4);
                const float xs[4] = {x4.x, x4.y, x4.z, x4.w};
#pragma unroll
                for (int kk = 0; kk < 4; ++kk)
#pragma unroll
                    for (int j = 0; j < 4; ++j)
                        acc[i][j] = fmaf(xs[kk], wv[kk][j], acc[i][j]);
            }
        }
    }

    if (cg < 10) {  // cols 4cg..4cg+3 < 40
#pragma unroll
        for (int i = 0; i < 4; ++i) {
            const int row = base + rg * 4 + i;
            if (row < n) {
                const float dv = dinv[row];
                union { __half2 h[2]; uint2 u; } pk;
                pk.h[0] = __floats2half2_rn(acc[i][0] * dv, acc[i][1] * dv);
                pk.h[1] = __floats2half2_rn(acc[i][2] * dv, acc[i][3] * dv);
                *(uint2*)(g + (size_t)row * 20 + cg * 2) = pk.u;
            }
        }
    }
}

// ---------------- gather2: out[d] = b2 + dinv[d]*(g2[d] + sum g2[s]) ----------------
__global__ __launch_bounds__(256) void k_gather2(const __half2* __restrict__ g,
                                                 const int* __restrict__ rowptr,
                                                 const int* __restrict__ csr_src,
                                                 const float* __restrict__ dinv,
                                                 const float* __restrict__ b2,
                                                 float* __restrict__ out, int n) {
    const int wave = threadIdx.x >> 6;
    const int lane = threadIdx.x & 63;
    const int d = blockIdx.x * 4 + wave;
    if (d >= n) return;
    const int f  = lane & 31;
    const int eg = lane >> 5;          // 0..1
    const int fc = (f < 20) ? f : 19;  // clamp so inactive lanes load safely
    const int beg = rowptr[d], end = rowptr[d + 1];
    float ax = 0.f, ay = 0.f;
    int p = beg + eg;
    for (; p + 2 < end; p += 4) {      // this eg handles p and p+2
        const int s0 = csr_src[p], s1 = csr_src[p + 2];
        const __half2 v0 = g[(size_t)s0 * 20 + fc];
        const __half2 v1 = g[(size_t)s1 * 20 + fc];
        const float2 f0 = __half22float2(v0), f1 = __half22float2(v1);
        ax += f0.x + f1.x;
        ay += f0.y + f1.y;
    }
    for (; p < end; p += 2) {
        const int s0 = csr_src[p];
        const float2 f0 = __half22float2(g[(size_t)s0 * 20 + fc]);
        ax += f0.x; ay += f0.y;
    }
    ax += __shfl_xor(ax, 32);
    ay += __shfl_xor(ay, 32);
    if (eg == 0 && f < 20) {
        const float2 fs = __half22float2(g[(size_t)d * 20 + f]);
        ax += fs.x; ay += fs.y;
        const float dd = dinv[d];
        const float2 bb = *(const float2*)(b2 + f * 2);
        float2 r;
        r.x = fmaf(dd, ax, bb.x);
        r.y = fmaf(dd, ay, bb.y);
        *(float2*)(out + (size_t)d * 40 + f * 2) = r;
    }
}

extern "C" void kernel_launch(void* const* d_in, const int* in_sizes, int n_in,
                              void* d_out, int out_size, void* d_ws, size_t ws_size,
                              hipStream_t stream) {
    const float* x  = (const float*)d_in[0];
    const int*   ei = (const int*)d_in[1];
    const float* W1 = (const float*)d_in[2];
    const float* b1 = (const float*)d_in[3];
    const float* W2 = (const float*)d_in[4];
    const float* b2 = (const float*)d_in[5];
    float* out = (float*)d_out;

    const int n = in_sizes[0] / 128;   // 50000
    const int e = in_sizes[1] / 2;     // 800000
    const int* src = ei;
    const int* dst = ei + e;

    const int n_pad = ((n + 63) / 64) * 64;
    const int e_pad = ((e + 63) / 64) * 64;
    const int NB    = (e + EPB - 1) / EPB;        // 391 (must be <= 512)
    const int nbuck = (n + 255) >> 8;             // 196 (must be <= 256)
    const int nbpad = ((NB + 63) / 64) * 64;      // 448

    // ws layout (4B units):
    //   dinv[n_pad] | rowptr[n_pad+64] | csr_src[e_pad] | g1[n_pad*64 ints] | out1[n*128]
    // sorted/Hmat/Off/btot/bbase overlay the g1 region (dead before k_gemm1 writes g1);
    // g2 (n*20 half2) overlays g1 (dead after k_gather1).
    float*   ws      = (float*)d_ws;
    float*   dinv    = ws;
    int*     rowptr  = (int*)(ws + n_pad);
    int*     csr_src = rowptr + n_pad + 64;
    __half2* g1      = (__half2*)(csr_src + e_pad);
    float*   out1    = (float*)((int*)g1 + (size_t)n_pad * 64);
    int2*    sorted  = (int2*)g1;                     // overlay: e_pad int2
    int*     Hmat    = (int*)g1 + (size_t)e_pad * 2;  // overlay: nbuck*nbpad
    int*     Off     = Hmat + nbuck * nbpad;          // overlay: nbuck*nbpad
    int*     btot    = Off + nbuck * nbpad;           // overlay: nbuck
    int*     bbase   = btot + ((nbuck + 63) / 64) * 64;  // overlay: nbuck+1
    __half2* g2      = g1;                            // overlay

    const int nb_rows = (n + 63) / 64;
    const int nb_g    = (n + 3) / 4;

    // CSR build: 2-level bucket sort, coalesced writes, zero global atomics
    k_hist <<<NB,    256, 0, stream>>>(dst, Hmat, e, nbuck, nbpad);
    k_bscan<<<nbuck, 256, 0, stream>>>(Hmat, Off, btot, NB, nbpad);
    k_base <<<1,     256, 0, stream>>>(btot, bbase, rowptr, nbuck, n, e);
    k_scat <<<NB,    256, 0, stream>>>(src, dst, Off, bbase, sorted, e, nbpad);
    k_bsort<<<nbuck, 256, 0, stream>>>(sorted, bbase, csr_src, rowptr, dinv, n);

    // layer 1
    k_gemm1  <<<nb_rows, 256, 0, stream>>>(x, W1, dinv, g1, n);
    k_gather1<<<nb_g, 256, 0, stream>>>(g1, rowptr, csr_src, dinv, b1, out1, n);

    // layer 2
    k_gemm2  <<<nb_rows, 256, 0, stream>>>(out1, W2, dinv, g2, n);
    k_gather2<<<nb_g, 256, 0, stream>>>(g2, rowptr, csr_src, dinv, b2, out, n);
}

// Round 8
// 136.930 us; speedup vs baseline: 1.6711x; 1.1547x over previous
//
#include <hip/hip_runtime.h>
#include <hip/hip_fp16.h>

#define THREADS 256
#define EPB 2048   // edges per block in hist/scat (256 thr x 8)
#define LDK 136    // padded K-stride for fp16 LDS tiles (128 + 8)

using f16x8 = __attribute__((ext_vector_type(8))) _Float16;
using f32x4 = __attribute__((ext_vector_type(4))) float;

// ================= sort-based CSR build (no global atomics) =================

__global__ __launch_bounds__(256) void k_hist(const int* __restrict__ dst,
                                              int* __restrict__ Hmat,
                                              int e, int nbuck, int nbpad) {
    __shared__ int h[256];
    const int t = threadIdx.x;
    h[t] = 0;
    __syncthreads();
    const int base = blockIdx.x * EPB;
#pragma unroll
    for (int k = 0; k < 8; ++k) {
        int i = base + k * 256 + t;
        if (i < e) atomicAdd(&h[dst[i] >> 8], 1);
    }
    __syncthreads();
    if (t < nbuck) Hmat[t * nbpad + blockIdx.x] = h[t];
}

__global__ __launch_bounds__(256) void k_bscan(const int* __restrict__ Hmat,
                                               int* __restrict__ Off,
                                               int* __restrict__ btot,
                                               int nb, int nbpad) {
    __shared__ int s[256];
    const int b = blockIdx.x, t = threadIdx.x;
    const int* H = Hmat + b * nbpad;
    const int v0 = (2 * t     < nb) ? H[2 * t]     : 0;
    const int v1 = (2 * t + 1 < nb) ? H[2 * t + 1] : 0;
    const int p = v0 + v1;
    s[t] = p;
    __syncthreads();
    for (int off = 1; off < 256; off <<= 1) {
        int w = (t >= off) ? s[t - off] : 0;
        __syncthreads();
        s[t] += w;
        __syncthreads();
    }
    const int excl = s[t] - p;
    int* O = Off + b * nbpad;
    if (2 * t     < nb) O[2 * t]     = excl;
    if (2 * t + 1 < nb) O[2 * t + 1] = excl + v0;
    if (t == 255) btot[b] = s[255];
}

__global__ __launch_bounds__(256) void k_base(const int* __restrict__ btot,
                                              int* __restrict__ bbase,
                                              int* __restrict__ rowptr,
                                              int nbuck, int n, int e) {
    __shared__ int s[256];
    const int t = threadIdx.x;
    const int v = (t < nbuck) ? btot[t] : 0;
    s[t] = v;
    __syncthreads();
    for (int off = 1; off < 256; off <<= 1) {
        int w = (t >= off) ? s[t - off] : 0;
        __syncthreads();
        s[t] += w;
        __syncthreads();
    }
    if (t < nbuck) bbase[t] = s[t] - v;
    if (t == 0) { bbase[nbuck] = e; rowptr[n] = e; }
}

__global__ __launch_bounds__(256) void k_scat(const int* __restrict__ src,
                                              const int* __restrict__ dst,
                                              const int* __restrict__ Off,
                                              const int* __restrict__ bbase,
                                              int2* __restrict__ sorted,
                                              int e, int nbpad) {
    __shared__ int h[256];
    const int t = threadIdx.x;
    h[t] = 0;
    __syncthreads();
    const int base = blockIdx.x * EPB;
#pragma unroll
    for (int k = 0; k < 8; ++k) {
        int i = base + k * 256 + t;
        if (i < e) {
            const int d = dst[i];
            const int b = d >> 8;
            const int r = atomicAdd(&h[b], 1);
            const int pos = bbase[b] + Off[b * nbpad + blockIdx.x] + r;
            sorted[pos] = make_int2(src[i], d);
        }
    }
}

__global__ __launch_bounds__(256) void k_bsort(const int2* __restrict__ sorted,
                                               const int* __restrict__ bbase,
                                               int* __restrict__ csr_src,
                                               int* __restrict__ rowptr,
                                               float* __restrict__ dinv, int n) {
    __shared__ int cnt[256];
    __shared__ int s[256];
    __shared__ int fil[256];
    const int b = blockIdx.x, t = threadIdx.x;
    const int lo = bbase[b], hi = bbase[b + 1];
    cnt[t] = 0;
    __syncthreads();
    for (int p = lo + t; p < hi; p += 256) atomicAdd(&cnt[sorted[p].y & 255], 1);
    __syncthreads();
    const int c = cnt[t];
    s[t] = c;
    __syncthreads();
    for (int off = 1; off < 256; off <<= 1) {
        int w = (t >= off) ? s[t - off] : 0;
        __syncthreads();
        s[t] += w;
        __syncthreads();
    }
    const int excl = s[t] - c;
    const int node = b * 256 + t;
    if (node < n) {
        rowptr[node] = lo + excl;
        dinv[node] = rsqrtf((float)(c + 1));
    }
    fil[t] = lo + excl;
    __syncthreads();
    for (int p = lo + t; p < hi; p += 256) {
        const int2 pr = sorted[p];
        const int pos = atomicAdd(&fil[pr.y & 255], 1);
        csr_src[pos] = pr.x;
    }
}

// ---------------- GEMM1 (MFMA f16): g1[n,128](fp16) = dinv * (x @ W1) ----------------
// 64 rows/block, 4 waves; wave = 16-row M-tile x 8 N-tiles; K=128 in 4 steps of 32.
__global__ __launch_bounds__(256) void k_gemm1(const float* __restrict__ x,
                                               const float* __restrict__ W,
                                               const float* __restrict__ dinv,
                                               __half* __restrict__ g, int n) {
    __shared__ _Float16 Wt[128 * LDK];  // W^T [n][k], 34816 B
    __shared__ _Float16 xl[64 * LDK];   // x   [r][k], 17408 B
    const int t  = threadIdx.x;
    const int wv = t >> 6;
    const int l  = t & 63;
    const int base = blockIdx.x * 64;

    // stage W^T (coalesced global read; scattered LDS write, pad breaks worst conflicts)
#pragma unroll
    for (int i = 0; i < 64; ++i) {
        const int idx = t + 256 * i;          // 16384
        const int nn = idx & 127, kk = idx >> 7;
        Wt[nn * LDK + kk] = (_Float16)W[kk * 128 + nn];
    }
    // stage x rows as fp16 (float4 read -> 4xfp16 write)
#pragma unroll
    for (int i = 0; i < 8; ++i) {
        const int idx = t + 256 * i;          // 2048 float4 chunks
        const int r = idx >> 5, c4 = idx & 31;
        const int row = base + r;
        float4 v = make_float4(0.f, 0.f, 0.f, 0.f);
        if (row < n) v = *(const float4*)(x + (size_t)row * 128 + c4 * 4);
        _Float16* p = xl + r * LDK + c4 * 4;
        p[0] = (_Float16)v.x; p[1] = (_Float16)v.y;
        p[2] = (_Float16)v.z; p[3] = (_Float16)v.w;
    }
    __syncthreads();

    f32x4 acc[8];
#pragma unroll
    for (int i = 0; i < 8; ++i) acc[i] = (f32x4){0.f, 0.f, 0.f, 0.f};

    const int arow = wv * 16 + (l & 15);
    const int koff = (l >> 4) * 8;
#pragma unroll
    for (int kb = 0; kb < 4; ++kb) {
        const f16x8 a = *(const f16x8*)(xl + arow * LDK + kb * 32 + koff);
#pragma unroll
        for (int nt = 0; nt < 8; ++nt) {
            const f16x8 b = *(const f16x8*)(Wt + (nt * 16 + (l & 15)) * LDK + kb * 32 + koff);
            acc[nt] = __builtin_amdgcn_mfma_f32_16x16x32_f16(a, b, acc[nt], 0, 0, 0);
        }
    }

    // C layout: row=(l>>4)*4+i, col=nt*16+(l&15)
#pragma unroll
    for (int i = 0; i < 4; ++i) {
        const int row = base + wv * 16 + (l >> 4) * 4 + i;
        if (row < n) {
            const float dv = dinv[row];
#pragma unroll
            for (int nt = 0; nt < 8; ++nt)
                g[(size_t)row * 128 + nt * 16 + (l & 15)] = __float2half(acc[nt][i] * dv);
        }
    }
}

// ---------------- gather1: out1h[d] = fp16(relu(b1 + dinv[d]*(g1[d] + sum g1[s]))) ----------------
__global__ __launch_bounds__(256) void k_gather1(const __half2* __restrict__ g,
                                                 const int* __restrict__ rowptr,
                                                 const int* __restrict__ csr_src,
                                                 const float* __restrict__ dinv,
                                                 const float* __restrict__ b1,
                                                 __half2* __restrict__ out1, int n) {
    const int wave = threadIdx.x >> 6;
    const int lane = threadIdx.x & 63;
    const int d = blockIdx.x * 4 + wave;
    if (d >= n) return;
    const int beg = rowptr[d], end = rowptr[d + 1];
    float ax = 0.f, ay = 0.f, bx = 0.f, by = 0.f;
    int p = beg;
    for (; p + 4 <= end; p += 4) {
        const int s0 = csr_src[p],     s1 = csr_src[p + 1];
        const int s2 = csr_src[p + 2], s3 = csr_src[p + 3];
        const __half2 v0 = g[(size_t)s0 * 64 + lane];
        const __half2 v1 = g[(size_t)s1 * 64 + lane];
        const __half2 v2 = g[(size_t)s2 * 64 + lane];
        const __half2 v3 = g[(size_t)s3 * 64 + lane];
        const float2 f0 = __half22float2(v0), f1 = __half22float2(v1);
        const float2 f2 = __half22float2(v2), f3 = __half22float2(v3);
        ax += f0.x + f2.x; ay += f0.y + f2.y;
        bx += f1.x + f3.x; by += f1.y + f3.y;
    }
    for (; p < end; ++p) {
        const int s0 = csr_src[p];
        const float2 f0 = __half22float2(g[(size_t)s0 * 64 + lane]);
        ax += f0.x; ay += f0.y;
    }
    const float2 fs = __half22float2(g[(size_t)d * 64 + lane]);
    ax += bx + fs.x;
    ay += by + fs.y;
    const float dd = dinv[d];
    const float2 bb = *(const float2*)(b1 + lane * 2);
    const float rx = fmaxf(fmaf(dd, ax, bb.x), 0.f);   // relu fused (out1 only feeds gemm2)
    const float ry = fmaxf(fmaf(dd, ay, bb.y), 0.f);
    out1[(size_t)d * 64 + lane] = __floats2half2_rn(rx, ry);
}

// ---------------- GEMM2 (MFMA f16): g2[n,40](fp16) = dinv * (out1h @ W2), N padded to 48 ----------------
__global__ __launch_bounds__(256) void k_gemm2(const __half* __restrict__ h1,
                                               const float* __restrict__ W,
                                               const float* __restrict__ dinv,
                                               __half* __restrict__ g, int n) {
    __shared__ _Float16 Wt[48 * LDK];   // W2^T [n][k], 13056 B (rows 40..47 zero)
    __shared__ _Float16 xl[64 * LDK];   // 17408 B
    const int t  = threadIdx.x;
    const int wv = t >> 6;
    const int l  = t & 63;
    const int base = blockIdx.x * 64;

#pragma unroll
    for (int i = 0; i < 24; ++i) {
        const int idx = t + 256 * i;          // 6144
        const int nn = idx % 48, kk = idx / 48;
        Wt[nn * LDK + kk] = (nn < 40) ? (_Float16)W[kk * 40 + nn] : (_Float16)0.f;
    }
    // stage out1h rows (already fp16): 16B chunks
#pragma unroll
    for (int i = 0; i < 4; ++i) {
        const int idx = t + 256 * i;          // 1024 chunks of 8 fp16
        const int r = idx >> 4, c8 = idx & 15;
        const int row = base + r;
        uint4 v = make_uint4(0u, 0u, 0u, 0u);
        if (row < n) v = *(const uint4*)(h1 + (size_t)row * 128 + c8 * 8);
        *(uint4*)(xl + r * LDK + c8 * 8) = v;
    }
    __syncthreads();

    f32x4 acc[3];
#pragma unroll
    for (int i = 0; i < 3; ++i) acc[i] = (f32x4){0.f, 0.f, 0.f, 0.f};

    const int arow = wv * 16 + (l & 15);
    const int koff = (l >> 4) * 8;
#pragma unroll
    for (int kb = 0; kb < 4; ++kb) {
        const f16x8 a = *(const f16x8*)(xl + arow * LDK + kb * 32 + koff);
#pragma unroll
        for (int nt = 0; nt < 3; ++nt) {
            const f16x8 b = *(const f16x8*)(Wt + (nt * 16 + (l & 15)) * LDK + kb * 32 + koff);
            acc[nt] = __builtin_amdgcn_mfma_f32_16x16x32_f16(a, b, acc[nt], 0, 0, 0);
        }
    }

#pragma unroll
    for (int i = 0; i < 4; ++i) {
        const int row = base + wv * 16 + (l >> 4) * 4 + i;
        if (row < n) {
            const float dv = dinv[row];
#pragma unroll
            for (int nt = 0; nt < 3; ++nt) {
                const int col = nt * 16 + (l & 15);
                if (col < 40)
                    g[(size_t)row * 40 + col] = __float2half(acc[nt][i] * dv);
            }
        }
    }
}

// ---------------- gather2: out[d] = b2 + dinv[d]*(g2[d] + sum g2[s]) ----------------
__global__ __launch_bounds__(256) void k_gather2(const __half2* __restrict__ g,
                                                 const int* __restrict__ rowptr,
                                                 const int* __restrict__ csr_src,
                                                 const float* __restrict__ dinv,
                                                 const float* __restrict__ b2,
                                                 float* __restrict__ out, int n) {
    const int wave = threadIdx.x >> 6;
    const int lane = threadIdx.x & 63;
    const int d = blockIdx.x * 4 + wave;
    if (d >= n) return;
    const int f  = lane & 31;
    const int eg = lane >> 5;          // 0..1
    const int fc = (f < 20) ? f : 19;  // clamp so inactive lanes load safely
    const int beg = rowptr[d], end = rowptr[d + 1];
    float ax = 0.f, ay = 0.f;
    int p = beg + eg;
    for (; p + 2 < end; p += 4) {
        const int s0 = csr_src[p], s1 = csr_src[p + 2];
        const __half2 v0 = g[(size_t)s0 * 20 + fc];
        const __half2 v1 = g[(size_t)s1 * 20 + fc];
        const float2 f0 = __half22float2(v0), f1 = __half22float2(v1);
        ax += f0.x + f1.x;
        ay += f0.y + f1.y;
    }
    for (; p < end; p += 2) {
        const int s0 = csr_src[p];
        const float2 f0 = __half22float2(g[(size_t)s0 * 20 + fc]);
        ax += f0.x; ay += f0.y;
    }
    ax += __shfl_xor(ax, 32);
    ay += __shfl_xor(ay, 32);
    if (eg == 0 && f < 20) {
        const float2 fs = __half22float2(g[(size_t)d * 20 + f]);
        ax += fs.x; ay += fs.y;
        const float dd = dinv[d];
        const float2 bb = *(const float2*)(b2 + f * 2);
        float2 r;
        r.x = fmaf(dd, ax, bb.x);
        r.y = fmaf(dd, ay, bb.y);
        *(float2*)(out + (size_t)d * 40 + f * 2) = r;
    }
}

extern "C" void kernel_launch(void* const* d_in, const int* in_sizes, int n_in,
                              void* d_out, int out_size, void* d_ws, size_t ws_size,
                              hipStream_t stream) {
    const float* x  = (const float*)d_in[0];
    const int*   ei = (const int*)d_in[1];
    const float* W1 = (const float*)d_in[2];
    const float* b1 = (const float*)d_in[3];
    const float* W2 = (const float*)d_in[4];
    const float* b2 = (const float*)d_in[5];
    float* out = (float*)d_out;

    const int n = in_sizes[0] / 128;   // 50000
    const int e = in_sizes[1] / 2;     // 800000
    const int* src = ei;
    const int* dst = ei + e;

    const int n_pad = ((n + 63) / 64) * 64;
    const int e_pad = ((e + 63) / 64) * 64;
    const int NB    = (e + EPB - 1) / EPB;        // 391
    const int nbuck = (n + 255) >> 8;             // 196
    const int nbpad = ((NB + 63) / 64) * 64;      // 448

    // ws layout (4B units):
    //   dinv[n_pad] | rowptr[n_pad+64] | csr_src[e_pad] | g1[n_pad*128 fp16] | out1h[n*128 fp16]
    // sorted/Hmat/Off/btot/bbase overlay g1 (dead before k_gemm1); g2 overlays g1 (dead after gather1).
    float*   ws      = (float*)d_ws;
    float*   dinv    = ws;
    int*     rowptr  = (int*)(ws + n_pad);
    int*     csr_src = rowptr + n_pad + 64;
    __half2* g1      = (__half2*)(csr_src + e_pad);      // n_pad*64 half2
    __half*  out1h   = (__half*)(g1 + (size_t)n_pad * 64);
    int2*    sorted  = (int2*)g1;                        // overlay
    int*     Hmat    = (int*)g1 + (size_t)e_pad * 2;     // overlay
    int*     Off     = Hmat + nbuck * nbpad;             // overlay
    int*     btot    = Off + nbuck * nbpad;              // overlay
    int*     bbase   = btot + ((nbuck + 63) / 64) * 64;  // overlay
    __half2* g2      = g1;                               // overlay

    const int nb_rows = (n + 63) / 64;
    const int nb_g    = (n + 3) / 4;

    // CSR build: 2-level bucket sort, coalesced writes, zero global atomics
    k_hist <<<NB,    256, 0, stream>>>(dst, Hmat, e, nbuck, nbpad);
    k_bscan<<<nbuck, 256, 0, stream>>>(Hmat, Off, btot, NB, nbpad);
    k_base <<<1,     256, 0, stream>>>(btot, bbase, rowptr, nbuck, n, e);
    k_scat <<<NB,    256, 0, stream>>>(src, dst, Off, bbase, sorted, e, nbpad);
    k_bsort<<<nbuck, 256, 0, stream>>>(sorted, bbase, csr_src, rowptr, dinv, n);

    // layer 1
    k_gemm1  <<<nb_rows, 256, 0, stream>>>(x, W1, dinv, (__half*)g1, n);
    k_gather1<<<nb_g, 256, 0, stream>>>(g1, rowptr, csr_src, dinv, b1, (__half2*)out1h, n);

    // layer 2
    k_gemm2  <<<nb_rows, 256, 0, stream>>>(out1h, W2, dinv, (__half*)g2, n);
    k_gather2<<<nb_g, 256, 0, stream>>>(g2, rowptr, csr_src, dinv, b2, out, n);
}

// Round 9
// 130.448 us; speedup vs baseline: 1.7541x; 1.0497x over previous
//
#include <hip/hip_runtime.h>
#include <hip/hip_fp16.h>

#define THREADS 256
#define EPB 2048   // edges per block in hist/scat (256 thr x 8)
#define LDK 136    // padded K-stride for fp16 LDS tiles (128 + 8)

using f16x8 = __attribute__((ext_vector_type(8))) _Float16;
using f32x4 = __attribute__((ext_vector_type(4))) float;

// ---------------- weight pre-convert: wt1h[nn][kk] = fp16(W1[kk][nn]); wt2h padded to 48 rows ----------------
__global__ __launch_bounds__(256) void k_wcvt(const float* __restrict__ W1,
                                              const float* __restrict__ W2,
                                              __half* __restrict__ wt1,
                                              __half* __restrict__ wt2) {
    const int idx = blockIdx.x * 256 + threadIdx.x;
    if (idx < 128 * 128) {
        const int nn = idx >> 7, kk = idx & 127;
        wt1[idx] = __float2half(W1[kk * 128 + nn]);
    } else {
        const int o = idx - 128 * 128;
        if (o < 48 * 128) {
            const int nn = o >> 7, kk = o & 127;
            wt2[o] = (nn < 40) ? __float2half(W2[kk * 40 + nn]) : __half(0.f);
        }
    }
}

// ================= sort-based CSR build (no global atomics) =================

__global__ __launch_bounds__(256) void k_hist(const int* __restrict__ dst,
                                              int* __restrict__ Hmat,
                                              int e, int nbuck, int nbpad) {
    __shared__ int h[256];
    const int t = threadIdx.x;
    h[t] = 0;
    __syncthreads();
    const int base4 = blockIdx.x * 512;   // int4 units
#pragma unroll
    for (int k = 0; k < 2; ++k) {
        const int i4 = base4 + k * 256 + t;
        const int i = i4 * 4;
        if (i + 3 < e) {
            const int4 d4 = ((const int4*)dst)[i4];
            atomicAdd(&h[d4.x >> 8], 1);
            atomicAdd(&h[d4.y >> 8], 1);
            atomicAdd(&h[d4.z >> 8], 1);
            atomicAdd(&h[d4.w >> 8], 1);
        } else {
            for (int j = i; j < e; ++j) atomicAdd(&h[dst[j] >> 8], 1);
        }
    }
    __syncthreads();
    if (t < nbuck) Hmat[t * nbpad + blockIdx.x] = h[t];
}

__global__ __launch_bounds__(256) void k_bscan(const int* __restrict__ Hmat,
                                               int* __restrict__ Off,
                                               int* __restrict__ btot,
                                               int nb, int nbpad) {
    __shared__ int s[256];
    const int b = blockIdx.x, t = threadIdx.x;
    const int* H = Hmat + b * nbpad;
    const int v0 = (2 * t     < nb) ? H[2 * t]     : 0;
    const int v1 = (2 * t + 1 < nb) ? H[2 * t + 1] : 0;
    const int p = v0 + v1;
    s[t] = p;
    __syncthreads();
    for (int off = 1; off < 256; off <<= 1) {
        int w = (t >= off) ? s[t - off] : 0;
        __syncthreads();
        s[t] += w;
        __syncthreads();
    }
    const int excl = s[t] - p;
    int* O = Off + b * nbpad;
    if (2 * t     < nb) O[2 * t]     = excl;
    if (2 * t + 1 < nb) O[2 * t + 1] = excl + v0;
    if (t == 255) btot[b] = s[255];
}

// scatter pairs into coarse buckets; per-block combined base table in LDS
__global__ __launch_bounds__(256) void k_scat(const int* __restrict__ src,
                                              const int* __restrict__ dst,
                                              const int* __restrict__ Off,
                                              const int* __restrict__ btot,
                                              int2* __restrict__ sorted,
                                              int e, int nbuck, int nbpad) {
    __shared__ int h[256];
    __shared__ int sc[256];
    __shared__ int comb[256];   // bbase[b] + Off[b][this block]
    const int t = threadIdx.x;
    const int v = (t < nbuck) ? btot[t] : 0;
    h[t] = 0;
    sc[t] = v;
    __syncthreads();
    for (int off = 1; off < 256; off <<= 1) {
        int w = (t >= off) ? sc[t - off] : 0;
        __syncthreads();
        sc[t] += w;
        __syncthreads();
    }
    comb[t] = (sc[t] - v) + ((t < nbuck) ? Off[t * nbpad + blockIdx.x] : 0);
    __syncthreads();

    const int base4 = blockIdx.x * 512;
#pragma unroll
    for (int k = 0; k < 2; ++k) {
        const int i4 = base4 + k * 256 + t;
        const int i = i4 * 4;
        if (i + 3 < e) {
            const int4 s4 = ((const int4*)src)[i4];
            const int4 d4 = ((const int4*)dst)[i4];
            {
                const int b = d4.x >> 8;
                sorted[comb[b] + atomicAdd(&h[b], 1)] = make_int2(s4.x, d4.x);
            }
            {
                const int b = d4.y >> 8;
                sorted[comb[b] + atomicAdd(&h[b], 1)] = make_int2(s4.y, d4.y);
            }
            {
                const int b = d4.z >> 8;
                sorted[comb[b] + atomicAdd(&h[b], 1)] = make_int2(s4.z, d4.z);
            }
            {
                const int b = d4.w >> 8;
                sorted[comb[b] + atomicAdd(&h[b], 1)] = make_int2(s4.w, d4.w);
            }
        } else {
            for (int j = i; j < e; ++j) {
                const int d = dst[j];
                const int b = d >> 8;
                sorted[comb[b] + atomicAdd(&h[b], 1)] = make_int2(src[j], d);
            }
        }
    }
}

// per-bucket counting sort by dst&255 -> csr_src contiguous; emits rowptr + dinv
__global__ __launch_bounds__(256) void k_bsort(const int2* __restrict__ sorted,
                                               const int* __restrict__ btot,
                                               int* __restrict__ csr_src,
                                               int* __restrict__ rowptr,
                                               float* __restrict__ dinv,
                                               int n, int nbuck, int e) {
    __shared__ int cnt[256];
    __shared__ int s[256];
    __shared__ int fil[256];
    const int b = blockIdx.x, t = threadIdx.x;

    // derive lo/hi from btot scan (replaces k_base)
    const int v = (t < nbuck) ? btot[t] : 0;
    s[t] = v;
    cnt[t] = 0;
    __syncthreads();
    for (int off = 1; off < 256; off <<= 1) {
        int w = (t >= off) ? s[t - off] : 0;
        __syncthreads();
        s[t] += w;
        __syncthreads();
    }
    const int hi = s[b];
    const int lo = hi - btot[b];
    __syncthreads();

    for (int p = lo + t; p < hi; p += 256) atomicAdd(&cnt[sorted[p].y & 255], 1);
    __syncthreads();
    const int c = cnt[t];
    s[t] = c;
    __syncthreads();
    for (int off = 1; off < 256; off <<= 1) {
        int w = (t >= off) ? s[t - off] : 0;
        __syncthreads();
        s[t] += w;
        __syncthreads();
    }
    const int excl = s[t] - c;
    const int node = b * 256 + t;
    if (node < n) {
        rowptr[node] = lo + excl;
        dinv[node] = rsqrtf((float)(c + 1));
    }
    if (b == 0 && t == 0) rowptr[n] = e;
    fil[t] = lo + excl;
    __syncthreads();
    for (int p = lo + t; p < hi; p += 256) {
        const int2 pr = sorted[p];
        const int pos = atomicAdd(&fil[pr.y & 255], 1);
        csr_src[pos] = pr.x;
    }
}

// ---------------- GEMM1 (MFMA f16): g1[n,128](fp16) = dinv * (x @ W1) ----------------
__global__ __launch_bounds__(256) void k_gemm1(const float* __restrict__ x,
                                               const __half* __restrict__ wt1,
                                               const float* __restrict__ dinv,
                                               __half* __restrict__ g, int n) {
    __shared__ _Float16 Wt[128 * LDK];  // W^T [nn][kk], 34816 B
    __shared__ _Float16 xl[64 * LDK];   // x   [r][kk], 17408 B
    const int t  = threadIdx.x;
    const int wv = t >> 6;
    const int l  = t & 63;
    const int base = blockIdx.x * 64;

    // stage pre-converted W^T: 2048 uint4 copies
    {
        const uint4* Wg = (const uint4*)wt1;
#pragma unroll
        for (int i = 0; i < 8; ++i) {
            const int idx = t + 256 * i;
            const int row = idx >> 4, c8 = idx & 15;
            *(uint4*)(Wt + row * LDK + c8 * 8) = Wg[idx];
        }
    }
    // stage x rows as packed fp16 (float4 -> uint2)
#pragma unroll
    for (int i = 0; i < 8; ++i) {
        const int idx = t + 256 * i;
        const int r = idx >> 5, c4 = idx & 31;
        const int row = base + r;
        float4 v = make_float4(0.f, 0.f, 0.f, 0.f);
        if (row < n) v = *(const float4*)(x + (size_t)row * 128 + c4 * 4);
        union { __half2 h2[2]; uint2 u; } pk;
        pk.h2[0] = __floats2half2_rn(v.x, v.y);
        pk.h2[1] = __floats2half2_rn(v.z, v.w);
        *(uint2*)(xl + r * LDK + c4 * 4) = pk.u;
    }
    __syncthreads();

    f32x4 acc[8];
#pragma unroll
    for (int i = 0; i < 8; ++i) acc[i] = (f32x4){0.f, 0.f, 0.f, 0.f};

    const int arow = wv * 16 + (l & 15);
    const int koff = (l >> 4) * 8;
#pragma unroll
    for (int kb = 0; kb < 4; ++kb) {
        const f16x8 a = *(const f16x8*)(xl + arow * LDK + kb * 32 + koff);
#pragma unroll
        for (int nt = 0; nt < 8; ++nt) {
            const f16x8 b = *(const f16x8*)(Wt + (nt * 16 + (l & 15)) * LDK + kb * 32 + koff);
            acc[nt] = __builtin_amdgcn_mfma_f32_16x16x32_f16(a, b, acc[nt], 0, 0, 0);
        }
    }

    // C layout: row=(l>>4)*4+i, col=nt*16+(l&15)
#pragma unroll
    for (int i = 0; i < 4; ++i) {
        const int row = base + wv * 16 + (l >> 4) * 4 + i;
        if (row < n) {
            const float dv = dinv[row];
#pragma unroll
            for (int nt = 0; nt < 8; ++nt)
                g[(size_t)row * 128 + nt * 16 + (l & 15)] = __float2half(acc[nt][i] * dv);
        }
    }
}

// ---------------- gather1: out1h[d] = fp16(relu(b1 + dinv[d]*(g1[d] + sum g1[s]))) ----------------
__global__ __launch_bounds__(256) void k_gather1(const __half2* __restrict__ g,
                                                 const int* __restrict__ rowptr,
                                                 const int* __restrict__ csr_src,
                                                 const float* __restrict__ dinv,
                                                 const float* __restrict__ b1,
                                                 __half2* __restrict__ out1, int n) {
    const int wave = threadIdx.x >> 6;
    const int lane = threadIdx.x & 63;
    const int d = blockIdx.x * 4 + wave;
    if (d >= n) return;
    const int beg = rowptr[d], end = rowptr[d + 1];
    float ax = 0.f, ay = 0.f, bx = 0.f, by = 0.f;
    int p = beg;
    for (; p + 4 <= end; p += 4) {
        const int s0 = csr_src[p],     s1 = csr_src[p + 1];
        const int s2 = csr_src[p + 2], s3 = csr_src[p + 3];
        const __half2 v0 = g[(size_t)s0 * 64 + lane];
        const __half2 v1 = g[(size_t)s1 * 64 + lane];
        const __half2 v2 = g[(size_t)s2 * 64 + lane];
        const __half2 v3 = g[(size_t)s3 * 64 + lane];
        const float2 f0 = __half22float2(v0), f1 = __half22float2(v1);
        const float2 f2 = __half22float2(v2), f3 = __half22float2(v3);
        ax += f0.x + f2.x; ay += f0.y + f2.y;
        bx += f1.x + f3.x; by += f1.y + f3.y;
    }
    for (; p < end; ++p) {
        const int s0 = csr_src[p];
        const float2 f0 = __half22float2(g[(size_t)s0 * 64 + lane]);
        ax += f0.x; ay += f0.y;
    }
    const float2 fs = __half22float2(g[(size_t)d * 64 + lane]);
    ax += bx + fs.x;
    ay += by + fs.y;
    const float dd = dinv[d];
    const float2 bb = *(const float2*)(b1 + lane * 2);
    const float rx = fmaxf(fmaf(dd, ax, bb.x), 0.f);
    const float ry = fmaxf(fmaf(dd, ay, bb.y), 0.f);
    out1[(size_t)d * 64 + lane] = __floats2half2_rn(rx, ry);
}

// ---------------- GEMM2 (MFMA f16): g2[n,40](fp16) = dinv * (out1h @ W2), N padded to 48 ----------------
__global__ __launch_bounds__(256) void k_gemm2(const __half* __restrict__ h1,
                                               const __half* __restrict__ wt2,
                                               const float* __restrict__ dinv,
                                               __half* __restrict__ g, int n) {
    __shared__ _Float16 Wt[48 * LDK];   // 13056 B
    __shared__ _Float16 xl[64 * LDK];   // 17408 B
    const int t  = threadIdx.x;
    const int wv = t >> 6;
    const int l  = t & 63;
    const int base = blockIdx.x * 64;

    {
        const uint4* Wg = (const uint4*)wt2;   // 768 uint4
#pragma unroll
        for (int i = 0; i < 3; ++i) {
            const int idx = t + 256 * i;
            const int row = idx >> 4, c8 = idx & 15;
            *(uint4*)(Wt + row * LDK + c8 * 8) = Wg[idx];
        }
    }
#pragma unroll
    for (int i = 0; i < 4; ++i) {
        const int idx = t + 256 * i;
        const int r = idx >> 4, c8 = idx & 15;
        const int row = base + r;
        uint4 v = make_uint4(0u, 0u, 0u, 0u);
        if (row < n) v = *(const uint4*)(h1 + (size_t)row * 128 + c8 * 8);
        *(uint4*)(xl + r * LDK + c8 * 8) = v;
    }
    __syncthreads();

    f32x4 acc[3];
#pragma unroll
    for (int i = 0; i < 3; ++i) acc[i] = (f32x4){0.f, 0.f, 0.f, 0.f};

    const int arow = wv * 16 + (l & 15);
    const int koff = (l >> 4) * 8;
#pragma unroll
    for (int kb = 0; kb < 4; ++kb) {
        const f16x8 a = *(const f16x8*)(xl + arow * LDK + kb * 32 + koff);
#pragma unroll
        for (int nt = 0; nt < 3; ++nt) {
            const f16x8 b = *(const f16x8*)(Wt + (nt * 16 + (l & 15)) * LDK + kb * 32 + koff);
            acc[nt] = __builtin_amdgcn_mfma_f32_16x16x32_f16(a, b, acc[nt], 0, 0, 0);
        }
    }

#pragma unroll
    for (int i = 0; i < 4; ++i) {
        const int row = base + wv * 16 + (l >> 4) * 4 + i;
        if (row < n) {
            const float dv = dinv[row];
#pragma unroll
            for (int nt = 0; nt < 3; ++nt) {
                const int col = nt * 16 + (l & 15);
                if (col < 40)
                    g[(size_t)row * 40 + col] = __float2half(acc[nt][i] * dv);
            }
        }
    }
}

// ---------------- gather2: out[d] = b2 + dinv[d]*(g2[d] + sum g2[s]) ----------------
// wave per node; 3 edge-groups x 20 feat-lanes (lanes 60..63 idle); shfl-reduce.
__global__ __launch_bounds__(256) void k_gather2(const __half2* __restrict__ g,
                                                 const int* __restrict__ rowptr,
                                                 const int* __restrict__ csr_src,
                                                 const float* __restrict__ dinv,
                                                 const float* __restrict__ b2,
                                                 float* __restrict__ out, int n) {
    const int wave = threadIdx.x >> 6;
    const int lane = threadIdx.x & 63;
    const int d = blockIdx.x * 4 + wave;
    if (d >= n) return;
    const int eg = lane / 20;          // 0..2 active, 3 idle
    const int f  = lane - eg * 20;
    const int beg = rowptr[d], end = rowptr[d + 1];
    float ax = 0.f, ay = 0.f;
    if (eg < 3) {
        for (int p = beg + eg; p < end; p += 3) {
            const int s0 = csr_src[p];
            const float2 f0 = __half22float2(g[(size_t)s0 * 20 + f]);
            ax += f0.x; ay += f0.y;
        }
    }
    ax += __shfl(ax, lane + 20) + __shfl(ax, lane + 40);
    ay += __shfl(ay, lane + 20) + __shfl(ay, lane + 40);
    if (lane < 20) {
        const float2 fs = __half22float2(g[(size_t)d * 20 + lane]);
        ax += fs.x; ay += fs.y;
        const float dd = dinv[d];
        const float2 bb = *(const float2*)(b2 + lane * 2);
        float2 r;
        r.x = fmaf(dd, ax, bb.x);
        r.y = fmaf(dd, ay, bb.y);
        *(float2*)(out + (size_t)d * 40 + lane * 2) = r;
    }
}

extern "C" void kernel_launch(void* const* d_in, const int* in_sizes, int n_in,
                              void* d_out, int out_size, void* d_ws, size_t ws_size,
                              hipStream_t stream) {
    const float* x  = (const float*)d_in[0];
    const int*   ei = (const int*)d_in[1];
    const float* W1 = (const float*)d_in[2];
    const float* b1 = (const float*)d_in[3];
    const float* W2 = (const float*)d_in[4];
    const float* b2 = (const float*)d_in[5];
    float* out = (float*)d_out;

    const int n = in_sizes[0] / 128;   // 50000
    const int e = in_sizes[1] / 2;     // 800000
    const int* src = ei;
    const int* dst = ei + e;

    const int n_pad = ((n + 63) / 64) * 64;
    const int e_pad = ((e + 63) / 64) * 64;
    const int NB    = (e + EPB - 1) / EPB;        // 391
    const int nbuck = (n + 255) >> 8;             // 196
    const int nbpad = ((NB + 63) / 64) * 64;      // 448

    // ws layout (4B units):
    //   dinv[n_pad] | rowptr[n_pad+64] | csr_src[e_pad] | g1[n_pad*128 fp16] | out1h[n_pad*128 fp16]
    //   | wt1h[128*128 fp16] | wt2h[48*128 fp16]
    // sorted/Hmat/Off/btot overlay g1 (dead before k_gemm1); g2 overlays g1 (dead after gather1).
    float*   ws      = (float*)d_ws;
    float*   dinv    = ws;
    int*     rowptr  = (int*)(ws + n_pad);
    int*     csr_src = rowptr + n_pad + 64;
    __half2* g1      = (__half2*)(csr_src + e_pad);      // n_pad*64 half2
    __half*  out1h   = (__half*)(g1 + (size_t)n_pad * 64);
    __half*  wt1h    = out1h + (size_t)n_pad * 128;
    __half*  wt2h    = wt1h + 128 * 128;
    int2*    sorted  = (int2*)g1;                        // overlay
    int*     Hmat    = (int*)g1 + (size_t)e_pad * 2;     // overlay
    int*     Off     = Hmat + nbuck * nbpad;             // overlay
    int*     btot    = Off + nbuck * nbpad;              // overlay
    __half2* g2      = g1;                               // overlay

    const int nb_rows = (n + 63) / 64;
    const int nb_g    = (n + 3) / 4;

    // weight pre-convert (independent of everything else)
    k_wcvt<<<(128 * 128 + 48 * 128 + 255) / 256, 256, 0, stream>>>(W1, W2, wt1h, wt2h);

    // CSR build: 2-level bucket sort, coalesced writes, zero global atomics
    k_hist <<<NB,    256, 0, stream>>>(dst, Hmat, e, nbuck, nbpad);
    k_bscan<<<nbuck, 256, 0, stream>>>(Hmat, Off, btot, NB, nbpad);
    k_scat <<<NB,    256, 0, stream>>>(src, dst, Off, btot, sorted, e, nbuck, nbpad);
    k_bsort<<<nbuck, 256, 0, stream>>>(sorted, btot, csr_src, rowptr, dinv, n, nbuck, e);

    // layer 1
    k_gemm1  <<<nb_rows, 256, 0, stream>>>(x, wt1h, dinv, (__half*)g1, n);
    k_gather1<<<nb_g, 256, 0, stream>>>(g1, rowptr, csr_src, dinv, b1, (__half2*)out1h, n);

    // layer 2
    k_gemm2  <<<nb_rows, 256, 0, stream>>>(out1h, wt2h, dinv, (__half*)g2, n);
    k_gather2<<<nb_g, 256, 0, stream>>>(g2, rowptr, csr_src, dinv, b2, out, n);
}